// Round 1
// baseline (238.088 us; speedup 1.0000x reference)
//
#include <hip/hip_runtime.h>
#include <hip/hip_bf16.h>
#include <math.h>

#define NCLS 20
#define KDIM 128
#define ALPHA 0.7f
#define BETA 1.5f

// ws layout (floats): [0, NCLS*KDIM) class sums; [NCLS*KDIM, +NCLS) counts;
//                     [NCLS*KDIM+NCLS, +NCLS) intra partial sums
#define WS_SUMS 0
#define WS_CNT (NCLS * KDIM)
#define WS_INTRA (NCLS * KDIM + NCLS)
#define WS_TOTAL (NCLS * KDIM + 2 * NCLS)

__global__ void k_init(float* ws) {
    int i = blockIdx.x * blockDim.x + threadIdx.x;
    if (i < WS_TOTAL) ws[i] = 0.0f;
}

// Pass 1: per-class embedding sums + counts.
// Layout: 256 threads = 8 points/iter, 32 lanes per point, each lane handles
// dims s, s+32, s+64, s+96 (LDS atomic bank = s -> conflict-free).
__global__ void __launch_bounds__(256) k_sums(const float* __restrict__ emb,
                                              const int* __restrict__ t,
                                              float* __restrict__ ws, int N) {
    __shared__ float lsum[NCLS * KDIM];
    __shared__ float lcnt[NCLS];
    const int tid = threadIdx.x;
    for (int i = tid; i < NCLS * KDIM; i += 256) lsum[i] = 0.0f;
    if (tid < NCLS) lcnt[tid] = 0.0f;
    __syncthreads();

    const int s = tid & 31;
    const int pp = tid >> 5;
    const int stride = gridDim.x * 8;
    for (int p = blockIdx.x * 8 + pp; p < N; p += stride) {
        const int c = t[p];
        const float* e = emb + (size_t)p * KDIM;
        float v0 = e[s], v1 = e[s + 32], v2 = e[s + 64], v3 = e[s + 96];
        float* base = lsum + c * KDIM + s;
        atomicAdd(base, v0);
        atomicAdd(base + 32, v1);
        atomicAdd(base + 64, v2);
        atomicAdd(base + 96, v3);
        if (s == 0) atomicAdd(&lcnt[c], 1.0f);
    }
    __syncthreads();
    for (int i = tid; i < NCLS * KDIM; i += 256) atomicAdd(&ws[WS_SUMS + i], lsum[i]);
    if (tid < NCLS) atomicAdd(&ws[WS_CNT + tid], lcnt[tid]);
}

// Pass 2: per-point distance to own-class mean, gated hinge^2, per-class sums.
__global__ void __launch_bounds__(256) k_intra(const float* __restrict__ emb,
                                               const int* __restrict__ t,
                                               const float* __restrict__ pts,
                                               float* __restrict__ ws, int N) {
    __shared__ float lmean[NCLS * KDIM];
    __shared__ float lintra[NCLS];
    const int tid = threadIdx.x;
    for (int i = tid; i < NCLS * KDIM; i += 256) {
        float cnt = ws[WS_CNT + i / KDIM];
        lmean[i] = ws[WS_SUMS + i] / fmaxf(cnt, 1.0f);
    }
    if (tid < NCLS) lintra[tid] = 0.0f;
    __syncthreads();

    const int s = tid & 31;
    const int pp = tid >> 5;
    const int stride = gridDim.x * 8;
    for (int p = blockIdx.x * 8 + pp; p < N; p += stride) {
        const int c = t[p];
        const float* e = emb + (size_t)p * KDIM;
        const float* m = lmean + c * KDIM + s;
        float d0 = e[s] - m[0];
        float d1 = e[s + 32] - m[32];
        float d2v = e[s + 64] - m[64];
        float d3 = e[s + 96] - m[96];
        float d2 = d0 * d0 + d1 * d1 + d2v * d2v + d3 * d3;
        // reduce across the 32-lane subgroup
        for (int off = 16; off >= 1; off >>= 1) d2 += __shfl_down(d2, off, 32);
        if (s == 0) {
            float d = sqrtf(d2);
            float px = pts[(size_t)p * 3 + 0];
            float py = pts[(size_t)p * 3 + 1];
            float pz = pts[(size_t)p * 3 + 2];
            float r = sqrtf(px * px + py * py + pz * pz);
            float g = 1.0f / (1.0f + expf(-r));
            float h = fmaxf(d - ALPHA, 0.0f);
            atomicAdd(&lintra[c], g * h * h);
        }
    }
    __syncthreads();
    if (tid < NCLS) atomicAdd(&ws[WS_INTRA + tid], lintra[tid]);
}

// Final: intra (clusters 1..19) + inter over 19x19 pair matrix -> scalar.
__global__ void __launch_bounds__(256) k_final(const float* __restrict__ ws,
                                               float* __restrict__ out) {
    __shared__ float lmean[NCLS * KDIM];
    __shared__ float red[256];
    const int tid = threadIdx.x;
    for (int i = tid; i < NCLS * KDIM; i += 256) {
        float cnt = ws[WS_CNT + i / KDIM];
        lmean[i] = ws[WS_SUMS + i] / fmaxf(cnt, 1.0f);
    }
    __syncthreads();

    float acc = 0.0f;
    // ordered pairs (i,j), i,j in [1,19], i != j  (19*19 = 361 cells)
    for (int idx = tid; idx < 361; idx += 256) {
        int i = idx / 19 + 1;
        int j = idx % 19 + 1;
        if (i != j) {
            float sq = 0.0f;
            const float* mi = lmean + i * KDIM;
            const float* mj = lmean + j * KDIM;
            for (int k = 0; k < KDIM; k++) {
                float df = mi[k] - mj[k];
                sq += df * df;
            }
            float dist = sqrtf(sq);
            float h = fmaxf(BETA - dist, 0.0f);
            acc += h * h;
        }
    }
    red[tid] = acc;
    __syncthreads();
    for (int st = 128; st >= 1; st >>= 1) {
        if (tid < st) red[tid] += red[tid + st];
        __syncthreads();
    }
    if (tid == 0) {
        float intra = 0.0f;
        for (int c = 1; c < NCLS; c++) {
            intra += ws[WS_INTRA + c] / fmaxf(ws[WS_CNT + c], 1.0f);
        }
        out[0] = intra / (float)NCLS + red[0] / (float)(NCLS * (NCLS - 1));
    }
}

extern "C" void kernel_launch(void* const* d_in, const int* in_sizes, int n_in,
                              void* d_out, int out_size, void* d_ws, size_t ws_size,
                              hipStream_t stream) {
    const float* pts = (const float*)d_in[0];
    const int* t = (const int*)d_in[1];
    const float* emb = (const float*)d_in[2];
    float* out = (float*)d_out;
    float* ws = (float*)d_ws;
    const int N = in_sizes[1];

    k_init<<<(WS_TOTAL + 255) / 256, 256, 0, stream>>>(ws);
    k_sums<<<1024, 256, 0, stream>>>(emb, t, ws, N);
    k_intra<<<1024, 256, 0, stream>>>(emb, t, pts, ws, N);
    k_final<<<1, 256, 0, stream>>>(ws, out);
}